// Round 8
// baseline (201.059 us; speedup 1.0000x reference)
//
#include <hip/hip_runtime.h>
#include <hip/hip_bf16.h>

#define NN 6144
#define HEADS 4
#define DIN 256
#define DOUT 64

typedef __bf16 bf16_t;
typedef bf16_t bf16x8 __attribute__((ext_vector_type(8)));
typedef float f32x16 __attribute__((ext_vector_type(16)));
typedef float f32x4 __attribute__((ext_vector_type(4)));
typedef unsigned u32x4 __attribute__((ext_vector_type(4)));

#if __has_builtin(__builtin_amdgcn_exp2f)
#define EXP2(x) __builtin_amdgcn_exp2f(x)
#else
#define EXP2(x) exp2f(x)
#endif

static __device__ __forceinline__ f32x16 zero16() {
  f32x16 z;
#pragma unroll
  for (int i = 0; i < 16; ++i) z[i] = 0.0f;
  return z;
}

static __device__ __forceinline__ bf16x8 ldg8(const bf16_t* p) {
  return *reinterpret_cast<const bf16x8*>(p);
}

static __device__ __forceinline__ unsigned pk2(float a, float b) {
  union { bf16_t h[2]; unsigned u; } z;
  z.h[0] = (bf16_t)a;
  z.h[1] = (bf16_t)b;
  return z.u;
}

// v_permlane32_swap_b32: x.hi32lanes <-> y.lo32lanes
static __device__ __forceinline__ void pswap(unsigned& x, unsigned& y) {
  asm("v_permlane32_swap_b32 %0, %1" : "+v"(x), "+v"(y));
}

// async global->LDS, 16B per lane. LDS dest = wave-uniform base + lane*16;
// global source is per-lane.
static __device__ __forceinline__ void gload_lds16(const float* g, float* lds) {
  __builtin_amdgcn_global_load_lds(
      (const __attribute__((address_space(1))) unsigned*)(uintptr_t)g,
      (__attribute__((address_space(3))) unsigned*)(unsigned)(uintptr_t)lds,
      16, 0, 0);
}

// ---------------- prep: h->bf16, W->bf16^T (Q-scale folded), zero out+denom
__global__ __launch_bounds__(256) void prep_kernel(
    const float* __restrict__ h, const float* __restrict__ WQ,
    const float* __restrict__ WK, const float* __restrict__ WV,
    bf16_t* __restrict__ hb, bf16_t* __restrict__ Wt,
    float* __restrict__ out, float* __restrict__ denom) {
  int stride = gridDim.x * blockDim.x;
  int idx = blockIdx.x * blockDim.x + threadIdx.x;
  for (int i = idx; i < HEADS * NN * DOUT; i += stride) out[i] = 0.0f;
  for (int i = idx; i < HEADS * NN; i += stride) denom[i] = 0.0f;
  for (int i = idx; i < NN * DIN; i += stride) hb[i] = (bf16_t)h[i];
  const float c2 = 0.0625f * 1.4426950408889634f;  // (1/sqrt(256)) * log2(e)
  for (int i = idx; i < 3 * HEADS * DOUT * DIN; i += stride) {
    int d = i & (DIN - 1);
    int o = (i >> 8) & (DOUT - 1);
    int hh = (i >> 14) & (HEADS - 1);
    int m = i >> 16;
    const float* W = (m == 0) ? WQ : (m == 1) ? WK : WV;
    float v = W[(hh * DIN + d) * DOUT + o];
    if (m == 0) v *= c2;
    Wt[i] = (bf16_t)v;  // Wt[m][hh][o][d]
  }
}

// ---------------- proj: Qb row-major [H][N][64]; Kf (A-frag) / Vf (B-frag).
// Kf elem(key,o):  h*393216 + (key>>6)*4096 + ((key>>5)&1)*2048 + (o>>4)*512
//                  + ((o>>3)&1)*256 + (key&31)*8 + (o&7)
// Vf elem(key,d):  h*393216 + (key>>6)*4096 + (d>>5)*2048 + ((key>>4)&3)*512
//                  + ((key>>3)&1)*256 + (d&31)*8 + (key&7)
__global__ __launch_bounds__(256) void proj_kernel(
    const bf16_t* __restrict__ hb, const bf16_t* __restrict__ Wt,
    const float* __restrict__ bQ, const float* __restrict__ bK,
    const float* __restrict__ bV,
    bf16_t* __restrict__ Qb, bf16_t* __restrict__ Kf, bf16_t* __restrict__ Vf) {
  const float c2 = 0.0625f * 1.4426950408889634f;
  int tid = threadIdx.x;
  int w = tid >> 6, l = tid & 63;
  int l31 = l & 31, lh = l >> 5;
  int hh = blockIdx.y;
  int n0 = blockIdx.x * 64;

#pragma unroll
  for (int s = 0; s < 3; ++s) {
    int t = w * 3 + s;  // 12 tiles: 0-3 Q, 4-7 K, 8-11 V
    if (t < 8) {
      int m = t >> 2;            // 0=Q, 1=K
      int rh = (t >> 1) & 1;     // row half (key half)
      int oh = t & 1;            // out-col half
      const bf16_t* arow = hb + (n0 + rh * 32 + l31) * DIN + 8 * lh;
      const bf16_t* brow = Wt + ((m * HEADS + hh) * DOUT + oh * 32 + l31) * DIN + 8 * lh;
      f32x16 acc = zero16();
#pragma unroll
      for (int kc = 0; kc < 16; ++kc)
        acc = __builtin_amdgcn_mfma_f32_32x32x16_bf16(ldg8(arow + kc * 16),
                                                      ldg8(brow + kc * 16), acc, 0, 0, 0);
      const float* bias = (m == 0) ? bQ : bK;
      float bv = bias[hh * DOUT + oh * 32 + l31];
      if (m == 0) {
        bv *= c2;
        bf16_t* outp = Qb + (size_t)(hh * NN + n0 + rh * 32) * DOUT + oh * 32 + l31;
#pragma unroll
        for (int r = 0; r < 16; ++r) {
          int q = (r & 3) + 8 * (r >> 2) + 4 * lh;
          outp[q * DOUT] = (bf16_t)(acc[r] + bv);
        }
      } else {
        int o = oh * 32 + l31;
        bf16_t* outp = Kf + (size_t)hh * 393216 + (n0 >> 6) * 4096 + rh * 2048 +
                       (o >> 4) * 512 + ((o >> 3) & 1) * 256 + (o & 7);
#pragma unroll
        for (int r = 0; r < 16; ++r) {
          int rr = (r & 3) + 8 * (r >> 2) + 4 * lh;  // key & 31
          outp[rr * 8] = (bf16_t)(acc[r] + bv);
        }
      }
    } else {
      int tt = t - 8;
      int oh = tt >> 1, nh = tt & 1;  // oh = d half, nh = key half
      const bf16_t* arow = Wt + ((2 * HEADS + hh) * DOUT + oh * 32 + l31) * DIN + 8 * lh;
      const bf16_t* brow = hb + (n0 + nh * 32 + l31) * DIN + 8 * lh;
      f32x16 acc = zero16();
#pragma unroll
      for (int kc = 0; kc < 16; ++kc)
        acc = __builtin_amdgcn_mfma_f32_32x32x16_bf16(ldg8(arow + kc * 16),
                                                      ldg8(brow + kc * 16), acc, 0, 0, 0);
      // B-frag layout: key = nh*32 + l31 fixed per thread; d = oh*32 + rr
      int k6 = nh * 32 + l31;
      bf16_t* outp = Vf + (size_t)hh * 393216 + (n0 >> 6) * 4096 + oh * 2048 +
                     (k6 >> 4) * 512 + ((k6 >> 3) & 1) * 256 + (k6 & 7);
#pragma unroll
      for (int r = 0; r < 16; ++r) {
        int rr = (r & 3) + 8 * (r >> 2) + 4 * lh;  // d & 31
        float bvv = bV[hh * DOUT + oh * 32 + rr];
        outp[rr * 8] = (bf16_t)(acc[r] + bvv);
      }
    }
  }
}

// ---------------- attention: 1-wave blocks, wave-private adj double-buffer,
// counted vmcnt, ZERO barriers. KSPLIT partial results combined via atomicAdd
// (no-max softmax => partials are additive).
__global__ __launch_bounds__(64, 2) void attn_kernel(
    const float* __restrict__ adj, const bf16_t* __restrict__ Qb,
    const bf16_t* __restrict__ Kf, const bf16_t* __restrict__ Vf,
    float* __restrict__ out, float* __restrict__ denom) {
  __shared__ __align__(16) float tile[2][32][64];  // 16 KB, wave-private

  int l = threadIdx.x;  // 0..63
  int l31 = l & 31, lh = l >> 5;

  // bijective XCD swizzle (3072 % 8 == 0): each XCD gets contiguous 384-block
  // chunk = 2 full (ky,hh) groups -> K/V stays L2-resident per XCD.
  int bid = blockIdx.x;
  int sb = (bid & 7) * 384 + (bid >> 3);
  int bx = sb % 192;        // q-tile
  int rem = sb / 192;       // 0..15
  int ky = rem & 3;         // key-split quarter
  int hh = rem >> 2;        // head
  int q0 = bx * 32;
  int ck0 = ky * 24;        // first 64-key chunk (within head)

  // Q as B-frag: col = q = l31, k = kc*16 + 8*lh + 0..7 (pre-scaled by c2)
  const bf16_t* Qrow = Qb + (size_t)(hh * NN + q0 + l31) * DOUT + 8 * lh;
  bf16x8 qf[4];
#pragma unroll
  for (int kc = 0; kc < 4; ++kc) qf[kc] = ldg8(Qrow + kc * 16);

  const bf16_t* Kh = Kf + (size_t)hh * 393216;
  const bf16_t* Vh = Vf + (size_t)hh * 393216;
  const float* adjbase = adj + (size_t)(hh * NN + q0) * NN + ky * 1536;

  // stage 8 KB tile (32 rows x 64 keys) for relative chunk CK into buf BUF.
  // instr i covers rows 4i..4i+3; source chunk XOR-pre-swizzled (4-bit).
#define STAGE(BUF, CK)                                                      \
  _Pragma("unroll") for (int i = 0; i < 8; ++i) {                           \
    int row = 4 * i + (l >> 4);                                             \
    int sc = (l & 15) ^ (row & 15);                                         \
    gload_lds16(adjbase + (size_t)row * NN + (CK) * 64 + sc * 4,            \
                &tile[BUF][4 * i][0]);                                      \
  }

  f32x16 o0 = zero16(), o1 = zero16();
  float sacc = 0.0f;

  STAGE(0, 0)  // prologue: 8 outstanding

  for (int it = 0; it < 24; ++it) {
    int buf = it & 1;
    int chunk = ck0 + it;

    // ---- K/V fragments (16 x dwordx4, contiguous 1KB each)
    const bf16_t* kbase = Kh + (size_t)chunk * 4096 + l * 8;
    const bf16_t* vbase = Vh + (size_t)chunk * 4096 + l * 8;
    bf16x8 kf[8], vf[8];
#pragma unroll
    for (int x = 0; x < 4; ++x) {
      kf[x] = ldg8(kbase + x * 512);
      kf[4 + x] = ldg8(kbase + 2048 + x * 512);
    }
#pragma unroll
    for (int x = 0; x < 4; ++x) {
      vf[x] = ldg8(vbase + x * 512);
      vf[4 + x] = ldg8(vbase + 2048 + x * 512);
    }
    __builtin_amdgcn_sched_barrier(0);

    // ---- stage next tile into other buffer (dummy re-stage on last iter
    // keeps the vmcnt count uniform; harmless, different buffer)
    int nt = (it + 1 < 24) ? it + 1 : 23;
    STAGE(buf ^ 1, nt)
    __builtin_amdgcn_sched_barrier(0);

    // ---- drain exactly stage(it): newer = 16 K/V + 8 stage(it+1) = 24.
    // No s_barrier: tile is wave-private.
    asm volatile("s_waitcnt vmcnt(24)" ::: "memory");
    __builtin_amdgcn_sched_barrier(0);

    // ---- adj readback: row = own q (l31), 4-bit XOR swizzle (2-way = free)
    f32x4 av[8];
#pragma unroll
    for (int t2 = 0; t2 < 2; ++t2)
#pragma unroll
      for (int g = 0; g < 4; ++g) {
        int c = 8 * t2 + 2 * g + lh;
        av[t2 * 4 + g] =
            *reinterpret_cast<const f32x4*>(&tile[buf][l31][(c ^ (l31 & 15)) << 2]);
      }

    // ---- S^T = K * Q^T : row = key (reg), col = q (lane)
    f32x16 s0 = zero16(), s1 = zero16();
#pragma unroll
    for (int kc = 0; kc < 4; ++kc) {
      s0 = __builtin_amdgcn_mfma_f32_32x32x16_bf16(kf[kc], qf[kc], s0, 0, 0, 0);
      s1 = __builtin_amdgcn_mfma_f32_32x32x16_bf16(kf[4 + kc], qf[kc], s1, 0, 0, 0);
    }

    // ---- P = exp2(S^T * adj); pack -> P-frag; O = P^T * V (pb as A-operand:
    // A/B fragments have identical lane/reg layout, so the same bits serve)
#pragma unroll
    for (int t2 = 0; t2 < 2; ++t2) {
      f32x16 st = t2 ? s1 : s0;
      float p[16];
#pragma unroll
      for (int r = 0; r < 16; ++r) {
        float pv = EXP2(st[r] * av[4 * t2 + (r >> 2)][r & 3]);
        p[r] = pv;
        sacc += pv;
      }
#pragma unroll
      for (int c = 0; c < 2; ++c) {
        unsigned wA0 = pk2(p[8 * c + 0], p[8 * c + 1]);
        unsigned wB0 = pk2(p[8 * c + 2], p[8 * c + 3]);
        unsigned wA1 = pk2(p[8 * c + 4], p[8 * c + 5]);
        unsigned wB1 = pk2(p[8 * c + 6], p[8 * c + 7]);
        pswap(wA0, wA1);
        pswap(wB0, wB1);
        u32x4 pw;
        pw[0] = wA0; pw[1] = wB0; pw[2] = wA1; pw[3] = wB1;
        bf16x8 pb = __builtin_bit_cast(bf16x8, pw);
        int kc = 2 * t2 + c;
        // O: row = q (from P^T), col = d (lane) -> coalesced epilogue
        o0 = __builtin_amdgcn_mfma_f32_32x32x16_bf16(pb, vf[kc], o0, 0, 0, 0);
        o1 = __builtin_amdgcn_mfma_f32_32x32x16_bf16(pb, vf[4 + kc], o1, 0, 0, 0);
      }
    }
  }

  // ---- epilogue: additive partials (no-max softmax) via atomicAdd.
  float stot = sacc + __shfl_xor(sacc, 32);
  if (l < 32) atomicAdd(&denom[hh * NN + q0 + l31], stot);
#pragma unroll
  for (int r = 0; r < 16; ++r) {
    int q = (r & 3) + 8 * (r >> 2) + 4 * lh;
    size_t base = (size_t)(hh * NN + q0 + q) * DOUT;
    atomicAdd(&out[base + l31], o0[r]);        // lanes = d 0..31: 128B line
    atomicAdd(&out[base + 32 + l31], o1[r]);   // lanes = d 32..63
  }
#undef STAGE
}

// ---------------- normalize: out /= denom, float4-vectorized, FULL coverage:
// 1536 blocks x 256 threads x 4 floats = 1,572,864 = HEADS*NN*DOUT exactly.
__global__ __launch_bounds__(256) void norm_kernel(
    float* __restrict__ out, const float* __restrict__ denom) {
  int i = blockIdx.x * 256 + threadIdx.x;  // float4 index
  float dn = denom[i >> 4];                // (i*4)/64 = i/16: same q for all 4
  f32x4 v = reinterpret_cast<f32x4*>(out)[i];
  float inv = 1.0f / dn;
#pragma unroll
  for (int j = 0; j < 4; ++j) v[j] *= inv;
  reinterpret_cast<f32x4*>(out)[i] = v;
}

extern "C" void kernel_launch(void* const* d_in, const int* in_sizes, int n_in,
                              void* d_out, int out_size, void* d_ws, size_t ws_size,
                              hipStream_t stream) {
  const float* adj = (const float*)d_in[0];
  const float* h   = (const float*)d_in[1];
  const float* WQ  = (const float*)d_in[2];
  const float* bQ  = (const float*)d_in[3];
  const float* WK  = (const float*)d_in[4];
  const float* bK  = (const float*)d_in[5];
  const float* WV  = (const float*)d_in[6];
  const float* bV  = (const float*)d_in[7];
  float* out = (float*)d_out;

  if (ws_size < 13074432) return;  // ~12.5 MB scratch

  char* ws = (char*)d_ws;
  bf16_t* hb    = (bf16_t*)ws;                 // [N][256] bf16           3,145,728 B
  bf16_t* Wt    = (bf16_t*)(ws + 3145728);     // [3][H][64][256] bf16      393,216 B
  bf16_t* Qb    = (bf16_t*)(ws + 3538944);     // [H][N][64] bf16 (scaled)3,145,728 B
  bf16_t* Kf    = (bf16_t*)(ws + 6684672);     // [H] K fragments         3,145,728 B
  bf16_t* Vf    = (bf16_t*)(ws + 9830400);     // [H] V fragments         3,145,728 B
  float*  denom = (float*)(ws + 12976128);     // [H][N] f32                 98,304 B

  prep_kernel<<<1024, 256, 0, stream>>>(h, WQ, WK, WV, hb, Wt, out, denom);
  proj_kernel<<<dim3(96, 4), 256, 0, stream>>>(hb, Wt, bQ, bK, bV, Qb, Kf, Vf);
  attn_kernel<<<3072, 64, 0, stream>>>(adj, Qb, Kf, Vf, out, denom);
  norm_kernel<<<1536, 256, 0, stream>>>(out, denom);
}